// Round 7
// baseline (826.904 us; speedup 1.0000x reference)
//
#include <hip/hip_runtime.h>
#include <cmath>

// Problem constants (N=2, S=512, C=512, H=W=50, OUT=7, RATIO=2)
#define NIMG 2
#define SPROP 512
#define NROI 1024          // NIMG*SPROP
#define CCH 512
#define FH 50
#define FW 50
#define K1 25088           // CCH*7*7
#define HID 1024
#define NCLS 21
#define NDET 100
#define IMGSZ 800.0f
#define LOGMAX 4.135166556742356f   // log(1000/16)
#define MCAND 10240        // SPROP*(NCLS-1)
#define ZSPLIT 8
#define KCHUNK 3136        // K1/ZSPLIT
#define ZSPLIT2 8
#define KCHUNK2 128        // HID/ZSPLIT2

typedef unsigned short u16;
typedef __attribute__((ext_vector_type(8))) short short8;
typedef __attribute__((ext_vector_type(4))) float f32x4;
typedef __attribute__((ext_vector_type(16))) float f32x16;

__device__ __forceinline__ u16 f2bf(float x) {        // RTNE fp32 -> bf16
  unsigned int u = __float_as_uint(x);
  u += 0x7fffu + ((u >> 16) & 1u);
  return (u16)(u >> 16);
}
__device__ __forceinline__ float bf2f(u16 h) {
  return __uint_as_float(((unsigned int)h) << 16);
}

// async global->LDS, 16B per lane; LDS dest = wave-uniform base + lane*16.
__device__ __forceinline__ void gld16(const u16* g, u16* l) {
  __builtin_amdgcn_global_load_lds(
      (const __attribute__((address_space(1))) void*)g,
      (__attribute__((address_space(3))) void*)l, 16, 0, 0);
}

// ------------------------------------------------------------ ROI align
// r4 structure (worked: roi fell out of top-5). Per-axis factorized meta in
// float4, pair-reads, conflict-free strides (273/17), reg prefetch of next
// 32-ch slab.
template <bool BF16OUT>
__global__ __launch_bounds__(256) void roi_kernel(
    const float* __restrict__ feat, const float* __restrict__ props,
    float* __restrict__ X, u16* __restrict__ Xhi, u16* __restrict__ Xlo) {
  const int r = blockIdx.x;
  const int n = r >> 9;
  const int tid = threadIdx.x;
  __shared__ float tile[32 * 273 + 16];   // 32 ch x (16x17 px) +pad, ~35 KB
  __shared__ float4 ymeta[14];  // {asf(rowoff0), asf(rowoff1), wy0, wy1}
  __shared__ float4 xmeta[14];  // {asf(px0), wxa, wxb, 0}
  __shared__ int smin[2];       // ymin, xmin

  const float p0 = props[r * 4 + 0] * 0.0625f;
  const float p1 = props[r * 4 + 1] * 0.0625f;
  const float p2 = props[r * 4 + 2] * 0.0625f;
  const float p3 = props[r * 4 + 3] * 0.0625f;
  const float bw = fmaxf(p2 - p0, 1.0f) / 7.0f;
  const float bh = fmaxf(p3 - p1, 1.0f) / 7.0f;

  if (tid < 14) {               // y-axis metadata
    const int j = tid;
    const float g = (float)(j >> 1) + ((float)(j & 1) + 0.5f) * 0.5f;
    const float y = p1 + g * bh;
    const float vy = (y > -1.0f && y < (float)FH) ? 0.5f : 0.0f;  // fold 0.5
    const float yc = fminf(fmaxf(y, 0.0f), (float)(FH - 1));
    const int y0 = (int)floorf(yc);
    const int y1 = min(y0 + 1, FH - 1);
    const float ly = yc - (float)y0;
    const float yc0 = fminf(fmaxf(p1 + 0.25f * bh, 0.0f), (float)(FH - 1));
    const int ymin = (int)floorf(yc0);
    float4 m;
    m.x = __int_as_float((y0 - ymin) * 17);
    m.y = __int_as_float((y1 - ymin) * 17);
    m.z = (1.0f - ly) * vy;
    m.w = ly * vy;
    ymeta[j] = m;
    if (j == 0) smin[0] = ymin;
  } else if (tid >= 16 && tid < 30) {   // x-axis metadata
    const int j = tid - 16;
    const float g = (float)(j >> 1) + ((float)(j & 1) + 0.5f) * 0.5f;
    const float x = p0 + g * bw;
    const float vx = (x > -1.0f && x < (float)FW) ? 0.5f : 0.0f;
    const float xc = fminf(fmaxf(x, 0.0f), (float)(FW - 1));
    const int x0 = (int)floorf(xc);
    const int x1 = min(x0 + 1, FW - 1);
    const float lx = xc - (float)x0;
    const float xc0 = fminf(fmaxf(p0 + 0.25f * bw, 0.0f), (float)(FW - 1));
    const int xmin = (int)floorf(xc0);
    const float wx0 = (1.0f - lx) * vx;
    const float wx1 = lx * vx;
    const int d = x1 - x0;      // 0 or 1
    float4 m;
    m.x = __int_as_float(x0 - xmin);
    m.y = wx0 + (d ? 0.0f : wx1);   // wxa
    m.z = d ? wx1 : 0.0f;           // wxb
    m.w = 0.0f;
    xmeta[j] = m;
    if (j == 0) smin[1] = xmin;
  }
  __syncthreads();

  const int ymin = smin[0], xmin = smin[1];
  const float* fb = feat + (size_t)n * CCH * (FH * FW);
  const int gy = min(ymin + (tid >> 4), FH - 1);
  const int gx = min(xmin + (tid & 15), FW - 1);
  const int offp = gy * FW + gx;
  const int wslot = (tid >> 4) * 17 + (tid & 15);
  const int q = tid & 7;        // output-slot group
  const int c = tid >> 3;       // channel within slab (0..31)
  const int cb = c * 273;

  float pf[32];
#pragma unroll
  for (int e = 0; e < 32; ++e) pf[e] = fb[(size_t)e * (FH * FW) + offp];

  for (int cc = 0; cc < 16; ++cc) {
#pragma unroll
    for (int e = 0; e < 32; ++e) tile[e * 273 + wslot] = pf[e];
    __syncthreads();
    if (cc < 15) {
      const float* fb2 = fb + (size_t)(cc + 1) * 32 * (FH * FW);
#pragma unroll
      for (int e = 0; e < 32; ++e) pf[e] = fb2[(size_t)e * (FH * FW) + offp];
    }
#pragma unroll
    for (int jj = 0; jj < 7; ++jj) {
      const int s = q + (jj << 3);
      if (s < 49) {
        const int oy = s / 7;
        const int ox = s - oy * 7;
        const float4 ym0 = ymeta[2 * oy];
        const float4 ym1 = ymeta[2 * oy + 1];
        const float4 xm0 = xmeta[2 * ox];
        const float4 xm1 = xmeta[2 * ox + 1];
        float acc = 0.0f;
#pragma unroll
        for (int sy = 0; sy < 2; ++sy) {
          const float4 ym = sy ? ym1 : ym0;
          const int ro0 = cb + __float_as_int(ym.x);
          const int ro1 = cb + __float_as_int(ym.y);
#pragma unroll
          for (int sx = 0; sx < 2; ++sx) {
            const float4 xm = sx ? xm1 : xm0;
            const int px = __float_as_int(xm.x);
            const float a0 = tile[ro0 + px];
            const float a1 = tile[ro0 + px + 1];
            const float b0 = tile[ro1 + px];
            const float b1 = tile[ro1 + px + 1];
            acc += ym.z * (xm.y * a0 + xm.z * a1) +
                   ym.w * (xm.y * b0 + xm.z * b1);
          }
        }
        const size_t k = (size_t)r * K1 + (size_t)(cc * 32 + c) * 49 + s;
        if (BF16OUT) {
          const u16 h = f2bf(acc);
          Xhi[k] = h;
          Xlo[k] = f2bf(acc - bf2f(h));
        } else {
          X[k] = acc;
        }
      }
    }
    __syncthreads();
  }
}

// ------------------------- w -> hi/lo bf16, transposed to [n][k]
template <int KDIM>
__global__ __launch_bounds__(256) void convw_kernel(
    const float* __restrict__ w, u16* __restrict__ Wh, u16* __restrict__ Wl) {
  __shared__ u16 sh[64][65], sl[64][65];
  const int k0 = blockIdx.x * 64;
  const int n0 = blockIdx.y * 64;
  const int t = threadIdx.x;
#pragma unroll
  for (int e = 0; e < 16; ++e) {
    const int idx = t + e * 256;
    const int kl = idx >> 6, nl = idx & 63;
    const float v = w[(size_t)(k0 + kl) * HID + n0 + nl];
    const u16 h = f2bf(v);
    sh[kl][nl] = h;
    sl[kl][nl] = f2bf(v - bf2f(h));
  }
  __syncthreads();
#pragma unroll
  for (int e = 0; e < 16; ++e) {
    const int idx = t + e * 256;
    const int nl = idx >> 6, kl = idx & 63;
    Wh[(size_t)(n0 + nl) * KDIM + k0 + kl] = sh[kl][nl];
    Wl[(size_t)(n0 + nl) * KDIM + k0 + kl] = sl[kl][nl];
  }
}

// --------------- split-bf16 MFMA GEMM (32x32x16), generic K-stride / K-chunk
// Round-13/14: T4 counted-vmcnt fix of r5's regression. r5 (dbuf + gload_lds +
// __syncthreads) DROPPED MfmaUtil 39->31: __syncthreads emits
// s_waitcnt vmcnt(0) before s_barrier, draining the next-buffer DMA queue
// every step (the documented m97 stall, recreated). Fix per T3/T4 (m201
// template idiom): raw s_barrier + inline-asm COUNTED vmcnt.
// Steady state per K=32 step (per wave, in-order vmcnt accounting, m135):
//   stage(cur^1): +6 DMA  -> outstanding = {6 oldest: cur} + {6 newest: cur^1}
//   s_waitcnt vmcnt(6)    -> retires exactly cur's 6
//   s_barrier             -> all waves: cur fully staged; compute may read
//   compute(cur)          -> ds_read (compiler lgkmcnt) + 24 MFMA
//   s_barrier             -> reads of cur retired; next step may overwrite
// Final step: vmcnt(0) (no new stage). sched_barrier(0) fences the compute
// cluster (rule #18 discipline). Data layout identical to r5 (verified
// passing): LDS dest linear (DMA), global source col pre-swizzled
// (chunk ^ ((row>>1)&3)), read-side vswz unchanged.
// A/B frag: [row = lane&31][k = (lane>>5)*8 + j].
// C/D: col = lane&31, row = (reg&3) + 8*(reg>>2) + 4*(lane>>5)  [m74/m101].
template <int KS, int KCH, bool SWZ>
__global__ __launch_bounds__(512, 2) void gemm_mfma_split(
    const u16* __restrict__ Ahg, const u16* __restrict__ Alg,
    const u16* __restrict__ Bhg, const u16* __restrict__ Blg,
    float* __restrict__ CP) {
  __shared__ u16 Ah[2][128][32], Al[2][128][32];
  __shared__ u16 Bh[2][256][32], Bl[2][256][32];
  const int tid = threadIdx.x;
  const int lane = tid & 63;
  const int wv = tid >> 6;           // 0..7
  const int wm = (wv >> 2) << 6;     // A row band {0,64}
  const int wn = (wv & 3) << 6;      // B col band {0,64,128,192}

  int bx = blockIdx.x, by = blockIdx.y, bz = blockIdx.z;
  if (SWZ) {
    // grid must be (4,8,8): XCD (= flat%8 under round-robin dispatch) <-> z.
    const int f = blockIdx.x + ((blockIdx.y + (blockIdx.z << 3)) << 2);
    bz = f & 7;
    const int u = f >> 3;            // 0..31
    bx = u & 3;
    by = u >> 2;
  }
  const int mT = by << 7;            // 128-row tiles
  const int nT = bx << 8;            // 256-col tiles
  const int kz = bz * KCH;
  constexpr int NSTEP = KCH / 32;

  // staging thread map: row sr = tid>>2, 16B chunk tid&3; LDS dest linear
  // (base + tid*16B), global col pre-swizzled (both-sides involution).
  const int sr = tid >> 2;                                  // 0..127
  const int sqw = (((tid & 3) ^ ((tid >> 3) & 3)) << 3);    // swizzled src col
  const size_t aoff  = (size_t)(mT + sr) * KS + sqw;
  const size_t b0off = (size_t)(nT + sr) * KS + sqw;
  const size_t b1off = (size_t)(nT + sr + 128) * KS + sqw;
  const int lofs = tid * 8;          // u16 units = tid*16 bytes

  f32x16 acc[2][2];
#pragma unroll
  for (int i = 0; i < 2; ++i)
#pragma unroll
    for (int j = 0; j < 2; ++j)
#pragma unroll
      for (int e = 0; e < 16; ++e) acc[i][j][e] = 0.0f;

  const int fm = lane & 31;          // row within 32-tile
  const int fh = lane >> 5;          // k-subgroup (0/1)
  const int vswz = (fm >> 1) & 3;    // read-side swizzle (row-derived)

  auto stage = [&](int buf, int kb) {
    gld16(Ahg + aoff + kb, &Ah[buf][0][0] + lofs);
    gld16(Alg + aoff + kb, &Al[buf][0][0] + lofs);
    gld16(Bhg + b0off + kb, &Bh[buf][0][0] + lofs);
    gld16(Bhg + b1off + kb, &Bh[buf][128][0] + lofs);
    gld16(Blg + b0off + kb, &Bl[buf][0][0] + lofs);
    gld16(Blg + b1off + kb, &Bl[buf][128][0] + lofs);
  };

  auto compute = [&](int buf) {
#pragma unroll
    for (int kh = 0; kh < 2; ++kh) {
      const int cA = ((((kh << 1) | fh) ^ vswz) << 3);
      short8 fa_h[2], fa_l[2], fb_h[2], fb_l[2];
#pragma unroll
      for (int t = 0; t < 2; ++t) {
        fa_h[t] = *(const short8*)(&Ah[buf][wm + t * 32 + fm][cA]);
        fa_l[t] = *(const short8*)(&Al[buf][wm + t * 32 + fm][cA]);
        fb_h[t] = *(const short8*)(&Bh[buf][wn + t * 32 + fm][cA]);
        fb_l[t] = *(const short8*)(&Bl[buf][wn + t * 32 + fm][cA]);
      }
#pragma unroll
      for (int ti = 0; ti < 2; ++ti)
#pragma unroll
        for (int tj = 0; tj < 2; ++tj) {
          acc[ti][tj] = __builtin_amdgcn_mfma_f32_32x32x16_bf16(
              fa_h[ti], fb_h[tj], acc[ti][tj], 0, 0, 0);
          acc[ti][tj] = __builtin_amdgcn_mfma_f32_32x32x16_bf16(
              fa_h[ti], fb_l[tj], acc[ti][tj], 0, 0, 0);
          acc[ti][tj] = __builtin_amdgcn_mfma_f32_32x32x16_bf16(
              fa_l[ti], fb_h[tj], acc[ti][tj], 0, 0, 0);
        }
    }
  };

  // prologue: stage step 0, full drain, barrier
  stage(0, kz);
  asm volatile("s_waitcnt vmcnt(0)" ::: "memory");
  __builtin_amdgcn_s_barrier();
  __builtin_amdgcn_sched_barrier(0);

  int cur = 0;
  for (int s = 0; s < NSTEP; ++s) {
    if (s + 1 < NSTEP) {
      stage(cur ^ 1, kz + (s + 1) * 32);          // +6 DMA (newest)
      asm volatile("s_waitcnt vmcnt(6)" ::: "memory");  // retire cur's 6
    } else {
      asm volatile("s_waitcnt vmcnt(0)" ::: "memory");  // last: drain all
    }
    __builtin_amdgcn_s_barrier();                 // cur staged for all waves
    __builtin_amdgcn_sched_barrier(0);
    compute(cur);
    __builtin_amdgcn_sched_barrier(0);
    __builtin_amdgcn_s_barrier();                 // reads done; may overwrite
    cur ^= 1;
  }

  float* Cp = CP + (size_t)bz * ((size_t)NROI * HID);   // bz: swizzled!
  const int ccol = nT + wn + fm;
  const int rbase = mT + wm + (fh << 2);
#pragma unroll
  for (int ti = 0; ti < 2; ++ti)
#pragma unroll
    for (int tj = 0; tj < 2; ++tj)
#pragma unroll
      for (int rg = 0; rg < 16; ++rg) {
        const int row = rbase + ti * 32 + (rg & 3) + 8 * (rg >> 2);
        Cp[(size_t)row * HID + ccol + tj * 32] = acc[ti][tj][rg];
      }
}

// ------------------------------------------------------- FC1 fallback (fp32)
__global__ __launch_bounds__(256) void gemm1_kernel(
    const float* __restrict__ A, const float* __restrict__ B,
    float* __restrict__ CP) {
  __shared__ float As[16][68];
  __shared__ float Bs[16][68];
  const int tid = threadIdx.x;
  const int mTile = blockIdx.y << 6;
  const int nTile = blockIdx.x << 6;
  const int k0 = blockIdx.z * KCHUNK;
  const int ty = tid >> 4, tx = tid & 15;
  const int ar = tid >> 2, ac = (tid & 3) << 2;
  const int br = tid >> 4, bcl = (tid & 15) << 2;
  float acc[4][4] = {};

  for (int kb = k0; kb < k0 + KCHUNK; kb += 16) {
    const float4 av = *(const float4*)(A + (size_t)(mTile + ar) * K1 + kb + ac);
    const float4 bv = *(const float4*)(B + (size_t)(kb + br) * HID + nTile + bcl);
    As[ac + 0][ar] = av.x; As[ac + 1][ar] = av.y;
    As[ac + 2][ar] = av.z; As[ac + 3][ar] = av.w;
    *(float4*)(&Bs[br][bcl]) = bv;
    __syncthreads();
#pragma unroll
    for (int kk = 0; kk < 16; ++kk) {
      const float4 a4 = *(const float4*)(&As[kk][ty << 2]);
      const float4 b4 = *(const float4*)(&Bs[kk][tx << 2]);
      const float aa[4] = {a4.x, a4.y, a4.z, a4.w};
      const float bb4[4] = {b4.x, b4.y, b4.z, b4.w};
#pragma unroll
      for (int i = 0; i < 4; ++i)
#pragma unroll
        for (int j = 0; j < 4; ++j)
          acc[i][j] = fmaf(aa[i], bb4[j], acc[i][j]);
    }
    __syncthreads();
  }
  float* Cp = CP + (size_t)blockIdx.z * (HID * NROI);
#pragma unroll
  for (int i = 0; i < 4; ++i) {
    *(float4*)(Cp + (size_t)(mTile + (ty << 2) + i) * HID + nTile + (tx << 2)) =
        make_float4(acc[i][0], acc[i][1], acc[i][2], acc[i][3]);
  }
}

// reduce 8 K-partials + bias + relu -> H1 as split-bf16 (feeds FC2 MFMA)
__global__ __launch_bounds__(256) void bias_relu_bf16_kernel(
    const float* __restrict__ CP, const float* __restrict__ b1,
    u16* __restrict__ H1h, u16* __restrict__ H1l) {
  const int idx = blockIdx.x * 256 + threadIdx.x;
  float v = b1[idx & (HID - 1)];
#pragma unroll
  for (int z = 0; z < ZSPLIT; ++z) v += CP[(size_t)z * (HID * NROI) + idx];
  v = fmaxf(v, 0.0f);
  const u16 h = f2bf(v);
  H1h[idx] = h;
  H1l[idx] = f2bf(v - bf2f(h));
}

// fp32 variant for the fallback path
__global__ __launch_bounds__(256) void bias_relu_f32_kernel(
    const float* __restrict__ CP, const float* __restrict__ b1,
    float* __restrict__ H1) {
  const int idx = blockIdx.x * 256 + threadIdx.x;
  float v = b1[idx & (HID - 1)];
#pragma unroll
  for (int z = 0; z < ZSPLIT; ++z) v += CP[(size_t)z * (HID * NROI) + idx];
  H1[idx] = fmaxf(v, 0.0f);
}

// reduce 8 K-partials of FC2 + bias + relu -> H2 fp32
__global__ __launch_bounds__(256) void bias_relu2_kernel(
    const float* __restrict__ CP2, const float* __restrict__ b2,
    float* __restrict__ H2) {
  const int idx = blockIdx.x * 256 + threadIdx.x;
  float v = b2[idx & (HID - 1)];
#pragma unroll
  for (int z = 0; z < ZSPLIT2; ++z) v += CP2[(size_t)z * (HID * NROI) + idx];
  H2[idx] = fmaxf(v, 0.0f);
}

// ------------------------------------------------------------- FC2 (K=1024)
// fp32 fallback only (bf16 path uses gemm_mfma_split<HID, KCHUNK2, true>)
__global__ __launch_bounds__(256) void gemm2_kernel(
    const float* __restrict__ A, const float* __restrict__ B,
    const float* __restrict__ bias, float* __restrict__ C) {
  __shared__ float As[16][68];
  __shared__ float Bs[16][68];
  const int tid = threadIdx.x;
  const int mTile = blockIdx.y << 6;
  const int nTile = blockIdx.x << 6;
  const int ty = tid >> 4, tx = tid & 15;
  const int ar = tid >> 2, ac = (tid & 3) << 2;
  const int br = tid >> 4, bcl = (tid & 15) << 2;
  float acc[4][4] = {};

  for (int kb = 0; kb < HID; kb += 16) {
    const float4 av = *(const float4*)(A + (size_t)(mTile + ar) * HID + kb + ac);
    const float4 bv = *(const float4*)(B + (size_t)(kb + br) * HID + nTile + bcl);
    As[ac + 0][ar] = av.x; As[ac + 1][ar] = av.y;
    As[ac + 2][ar] = av.z; As[ac + 3][ar] = av.w;
    *(float4*)(&Bs[br][bcl]) = bv;
    __syncthreads();
#pragma unroll
    for (int kk = 0; kk < 16; ++kk) {
      const float4 a4 = *(const float4*)(&As[kk][ty << 2]);
      const float4 b4 = *(const float4*)(&Bs[kk][tx << 2]);
      const float aa[4] = {a4.x, a4.y, a4.z, a4.w};
      const float bb4[4] = {b4.x, b4.y, b4.z, b4.w};
#pragma unroll
      for (int i = 0; i < 4; ++i)
#pragma unroll
        for (int j = 0; j < 4; ++j)
          acc[i][j] = fmaf(aa[i], bb4[j], acc[i][j]);
    }
    __syncthreads();
  }
#pragma unroll
  for (int i = 0; i < 4; ++i) {
#pragma unroll
    for (int j = 0; j < 4; ++j) {
      float v = acc[i][j] + bias[nTile + (tx << 2) + j];
      acc[i][j] = fmaxf(v, 0.0f);
    }
    *(float4*)(C + (size_t)(mTile + (ty << 2) + i) * HID + nTile + (tx << 2)) =
        make_float4(acc[i][0], acc[i][1], acc[i][2], acc[i][3]);
  }
}

// ------------------- heads: cls+box dots, softmax, decode, candidate arrays
// Candidate layout is CLASS-MAJOR: index = n*MCAND + (k-1)*SPROP + s
__global__ __launch_bounds__(128) void heads_kernel(
    const float* __restrict__ H2m, const float* __restrict__ wc,
    const float* __restrict__ bc, const float* __restrict__ wb,
    const float* __restrict__ bb, const float* __restrict__ props,
    float* __restrict__ BX2, float* __restrict__ NB2,
    float* __restrict__ LV2) {
  const int r = blockIdx.x;
  const int tid = threadIdx.x;
  __shared__ float hrow[HID];
  __shared__ float vals[112];
  __shared__ float red[2];

  for (int i = tid; i < HID; i += 128) hrow[i] = H2m[(size_t)r * HID + i];
  __syncthreads();

  if (tid < 105) {
    float acc;
    if (tid < NCLS) {
      acc = bc[tid];
      for (int kk = 0; kk < HID; ++kk) acc = fmaf(hrow[kk], wc[kk * NCLS + tid], acc);
    } else {
      const int j = tid - NCLS;
      acc = bb[j];
      for (int kk = 0; kk < HID; ++kk) acc = fmaf(hrow[kk], wb[kk * (NCLS * 4) + j], acc);
    }
    vals[tid] = acc;
  }
  __syncthreads();

  if (tid == 0) {
    float m = vals[0];
    for (int k = 1; k < NCLS; ++k) m = fmaxf(m, vals[k]);
    float s = 0.0f;
    for (int k = 0; k < NCLS; ++k) s += expf(vals[k] - m);
    red[0] = m;
    red[1] = 1.0f / s;
  }
  __syncthreads();

  if (tid >= 1 && tid <= 20) {
    const int k = tid;
    const float prob = expf(vals[k] - red[0]) * red[1];

    const float px1 = props[r * 4 + 0], py1 = props[r * 4 + 1];
    const float px2 = props[r * 4 + 2], py2 = props[r * 4 + 3];
    const float pw = px2 - px1, ph = py2 - py1;
    const float pcx = px1 + 0.5f * pw, pcy = py1 + 0.5f * ph;

    const float dx = vals[NCLS + k * 4 + 0] / 10.0f;
    const float dy = vals[NCLS + k * 4 + 1] / 10.0f;
    const float dw = fminf(vals[NCLS + k * 4 + 2] / 5.0f, LOGMAX);
    const float dh = fminf(vals[NCLS + k * 4 + 3] / 5.0f, LOGMAX);

    const float cx = dx * pw + pcx, cy = dy * ph + pcy;
    const float w = expf(dw) * pw, h = expf(dh) * ph;
    float b0 = cx - 0.5f * w, b1c = cy - 0.5f * h;
    float b2 = cx + 0.5f * w, b3 = cy + 0.5f * h;
    b0 = fminf(fmaxf(b0, 0.0f), IMGSZ);
    b1c = fminf(fmaxf(b1c, 0.0f), IMGSZ);
    b2 = fminf(fmaxf(b2, 0.0f), IMGSZ);
    b3 = fminf(fmaxf(b3, 0.0f), IMGSZ);

    const float wv = b2 - b0, hv = b3 - b1c;
    const bool valid = (prob > 0.05f) && (wv >= 0.01f) && (hv >= 0.01f);

    const int n = r >> 9, s = r & 511;
    const int cand = (k - 1) * SPROP + s;     // class-major
    const size_t bi = (size_t)n * MCAND + cand;
    const float off = (float)k * (IMGSZ + 1.0f);

    BX2[bi * 4 + 0] = b0; BX2[bi * 4 + 1] = b1c;
    BX2[bi * 4 + 2] = b2; BX2[bi * 4 + 3] = b3;
    NB2[bi * 4 + 0] = b0 + off; NB2[bi * 4 + 1] = b1c + off;
    NB2[bi * 4 + 2] = b2 + off; NB2[bi * 4 + 3] = b3 + off;
    LV2[bi] = valid ? prob : -1.0f;
  }
}

// ---------------------------------------------- per-(image,class) greedy NMS
// Cross-class IoU == 0 (801*k offsets), so the global greedy restricted to a
// class equals the standalone per-class greedy (proved by induction on picks).
// One wave per (n,c): 512 slots in registers, barrier-free serial loop.
template <int CTRL>
__device__ __forceinline__ void red2(float& v, int& ix) {
  const float tv = __int_as_float(__builtin_amdgcn_update_dpp(
      (int)0xC0000000, __float_as_int(v), CTRL, 0xf, 0xf, false));
  const int ti = __builtin_amdgcn_update_dpp(0x7fffffff, ix, CTRL, 0xf, 0xf, false);
  if (tv > v || (tv == v && ti < ix)) { v = tv; ix = ti; }
}
__device__ __forceinline__ void wave_red2(float& v, int& ix) {
  red2<0x111>(v, ix);  // row_shr:1
  red2<0x112>(v, ix);  // row_shr:2
  red2<0x114>(v, ix);  // row_shr:4
  red2<0x118>(v, ix);  // row_shr:8
  red2<0x142>(v, ix);  // row_bcast:15
  red2<0x143>(v, ix);  // row_bcast:31 -> lane 63 holds winner
}

__global__ __launch_bounds__(64) void nms_class_kernel(
    const float* __restrict__ NB2, const float* __restrict__ LV2,
    float* __restrict__ ksg, int* __restrict__ kig, int* __restrict__ cntg) {
  const int bid = blockIdx.x;           // n*20 + c
  const int lane = threadIdx.x;         // 0..63
  __shared__ float4 lbox[SPROP];        // winner-broadcast copy
  const size_t cb = (size_t)bid * SPROP;

  float lv[8], b0[8], b1[8], b2[8], b3[8], ar[8];
#pragma unroll
  for (int j = 0; j < 8; ++j) {
    const int s = lane + j * 64;
    lv[j] = LV2[cb + s];
    const float4 b = *(const float4*)(NB2 + (cb + s) * 4);
    b0[j] = b.x; b1[j] = b.y; b2[j] = b.z; b3[j] = b.w;
    ar[j] = (b.z - b.x) * (b.w - b.y);
    lbox[s] = b;
  }

  int cnt = 0;
  for (int d = 0; d < NDET; ++d) {
    float bv = -2.0f;
    int bix = 0x7fffffff;
#pragma unroll
    for (int j = 0; j < 8; ++j) {     // j asc => slot asc; strict > keeps lowest
      if (lv[j] > bv) { bv = lv[j]; bix = lane + j * 64; }
    }
    wave_red2(bv, bix);
    const float bv2 = __shfl(bv, 63);
    const int bix2 = __shfl(bix, 63);
    if (bv2 <= 0.05f) break;          // all remaining dead; wave-uniform

    if (lane == 0) {
      ksg[bid * NDET + cnt] = bv2;
      kig[bid * NDET + cnt] = bix2;   // slot within class (0..511)
    }
    ++cnt;

    const float4 wb = lbox[bix2];     // same-wave LDS write->read, waitcnt ok
    const float wa = (wb.z - wb.x) * (wb.w - wb.y);
#pragma unroll
    for (int j = 0; j < 8; ++j) {
      const float xx1 = fmaxf(wb.x, b0[j]);
      const float yy1 = fmaxf(wb.y, b1[j]);
      const float xx2 = fminf(wb.z, b2[j]);
      const float yy2 = fminf(wb.w, b3[j]);
      const float inter = fmaxf(xx2 - xx1, 0.0f) * fmaxf(yy2 - yy1, 0.0f);
      const float iou = inter / (wa + ar[j] - inter + 1e-9f);
      if (iou > 0.5f) lv[j] = -1.0f;
    }
  }
  if (lane == 0) cntg[bid] = cnt;
}

// ------------------------------- merge: top-100 by (score desc, flat-idx asc)
// Global greedy order == keeps sorted by packed priority (scores non-increasing
// along greedy; tied keeps are simultaneously live so argmax first-index rule
// = lowest flat idx). Rank-based selection: zero barriers in the hot loop.
__global__ __launch_bounds__(1024) void nms_merge_kernel(
    const float* __restrict__ ksg, const int* __restrict__ kig,
    const int* __restrict__ cntg, const float* __restrict__ BX2,
    float* __restrict__ out) {
  const int n = blockIdx.x;
  const int tid = threadIdx.x;
  __shared__ int cbase[21];
  __shared__ unsigned long long keys[2000];
  __shared__ float ssc[2000];
  __shared__ int sfl[2000];
  __shared__ float svals[NDET];
  __shared__ int sflat[NDET];

  if (tid == 0) {
    int acc = 0;
    for (int c = 0; c < 20; ++c) { cbase[c] = acc; acc += cntg[n * 20 + c]; }
    cbase[20] = acc;
  }
  __syncthreads();
  const int T = cbase[20];     // <= 2000

  for (int idx = tid; idx < 20 * NDET; idx += 1024) {
    const int c = idx / NDET, e = idx - (idx / NDET) * NDET;
    if (e < cntg[n * 20 + c]) {
      const int pos = cbase[c] + e;
      const float s = ksg[(n * 20 + c) * NDET + e];
      const int slot = kig[(n * 20 + c) * NDET + e];
      const int flat = slot * 20 + c;            // original flat candidate idx
      ssc[pos] = s;
      sfl[pos] = flat;
      keys[pos] = ((unsigned long long)__float_as_uint(s) << 32) |
                  (unsigned long long)(0xFFFFFFFFu - (unsigned)flat);
    }
  }
  __syncthreads();

  float msc[2]; int mfl[2]; unsigned long long mk[2]; int rank[2] = {0, 0};
  bool own[2];
#pragma unroll
  for (int e = 0; e < 2; ++e) {
    const int i = tid + e * 1024;
    own[e] = (i < T);
    if (own[e]) { mk[e] = keys[i]; msc[e] = ssc[i]; mfl[e] = sfl[i]; }
  }
  for (int i = 0; i < T; ++i) {        // LDS broadcast read per iteration
    const unsigned long long k = keys[i];
    if (own[0] && k > mk[0]) ++rank[0];
    if (own[1] && k > mk[1]) ++rank[1];
  }
#pragma unroll
  for (int e = 0; e < 2; ++e)
    if (own[e] && rank[e] < NDET) { svals[rank[e]] = msc[e]; sflat[rank[e]] = mfl[e]; }
  __syncthreads();

  if (tid < NDET) {
    const int m = (T < NDET) ? T : NDET;
    const bool keep = tid < m;
    float sv = 0.0f;
    float4 bx4 = make_float4(0.0f, 0.0f, 0.0f, 0.0f);
    float label = 0.0f;
    if (keep) {
      sv = svals[tid];
      const int flat = sflat[tid];
      const int c = flat % 20, s = flat / 20;
      bx4 = *(const float4*)(BX2 + ((size_t)(n * 20 + c) * SPROP + s) * 4);
      label = (float)(c + 1);
    }
    out[(n * NDET + tid) * 4 + 0] = bx4.x;
    out[(n * NDET + tid) * 4 + 1] = bx4.y;
    out[(n * NDET + tid) * 4 + 2] = bx4.z;
    out[(n * NDET + tid) * 4 + 3] = bx4.w;
    out[NIMG * NDET * 4 + n * NDET + tid] = sv;
    out[NIMG * NDET * 4 + NIMG * NDET + n * NDET + tid] = label;
  }
}

// ---------------------------------------------------------------- launcher
extern "C" void kernel_launch(void* const* d_in, const int* in_sizes, int n_in,
                              void* d_out, int out_size, void* d_ws, size_t ws_size,
                              hipStream_t stream) {
  const float* features  = (const float*)d_in[0];
  const float* proposals = (const float*)d_in[1];
  const float* w1 = (const float*)d_in[2];
  const float* b1 = (const float*)d_in[3];
  const float* w2 = (const float*)d_in[4];
  const float* b2 = (const float*)d_in[5];
  const float* wc = (const float*)d_in[6];
  const float* bc = (const float*)d_in[7];
  const float* wb = (const float*)d_in[8];
  const float* bb = (const float*)d_in[9];

  const size_t XE = (size_t)NROI * K1;
  const size_t WE = (size_t)K1 * HID;
  const size_t FLOATS_TAIL =
      (size_t)ZSPLIT * NROI * HID + 2 * (size_t)NROI * HID + (size_t)NIMG * MCAND * 10;
  const size_t NEED = (XE * 2 + WE * 2) * sizeof(u16) + FLOATS_TAIL * sizeof(float);

  if (ws_size >= NEED) {
    u16* Xhi = (u16*)d_ws;
    u16* Xlo = Xhi + XE;
    u16* Wh  = Xlo + XE;
    u16* Wl  = Wh + WE;
    float* CP  = (float*)(Wl + WE);
    // CP region: 8 partials (33.5 MB); FC2's 8 partials (CP2) alias it —
    // CP is dead after bias_relu_bf16, CP2 written only by the later FC2.
    float* CP2 = CP;
    float* H2  = CP + (size_t)ZSPLIT * NROI * HID;
    float* BX2 = H2 + (size_t)NROI * HID;
    float* NB2 = BX2 + (size_t)NIMG * MCAND * 4;
    float* LV2 = NB2 + (size_t)NIMG * MCAND * 4;
    float* ksg = LV2 + (size_t)NIMG * MCAND;
    int*   kig = (int*)(ksg + (size_t)NIMG * 20 * NDET);
    int*   cntg = kig + (size_t)NIMG * 20 * NDET;
    // H1 hi/lo alias the Xhi region (dead after FC1); W2t hi/lo alias Xlo.
    // Stream order guarantees safety: gemm1 reads X before these are written.
    u16* H1h = Xhi;
    u16* H1l = Xhi + (size_t)NROI * HID;
    u16* W2h = Xlo;
    u16* W2l = Xlo + (size_t)HID * HID;

    convw_kernel<K1><<<dim3(K1 / 64, HID / 64), 256, 0, stream>>>(w1, Wh, Wl);
    roi_kernel<true><<<NROI, 256, 0, stream>>>(features, proposals, nullptr, Xhi, Xlo);
    gemm_mfma_split<K1, KCHUNK, true><<<dim3(4, 8, ZSPLIT), 512, 0, stream>>>(
        Xhi, Xlo, Wh, Wl, CP);
    bias_relu_bf16_kernel<<<(NROI * HID) / 256, 256, 0, stream>>>(CP, b1, H1h, H1l);
    convw_kernel<HID><<<dim3(HID / 64, HID / 64), 256, 0, stream>>>(w2, W2h, W2l);
    gemm_mfma_split<HID, KCHUNK2, true><<<dim3(4, 8, ZSPLIT2), 512, 0, stream>>>(
        H1h, H1l, W2h, W2l, CP2);
    bias_relu2_kernel<<<(NROI * HID) / 256, 256, 0, stream>>>(CP2, b2, H2);
    heads_kernel<<<NROI, 128, 0, stream>>>(H2, wc, bc, wb, bb, proposals,
                                           BX2, NB2, LV2);
    nms_class_kernel<<<NIMG * 20, 64, 0, stream>>>(NB2, LV2, ksg, kig, cntg);
    nms_merge_kernel<<<NIMG, 1024, 0, stream>>>(ksg, kig, cntg, BX2,
                                                (float*)d_out);
  } else {
    float* ws = (float*)d_ws;
    float* X   = ws;
    float* CP  = X + XE;
    float* H1  = CP + (size_t)ZSPLIT * NROI * HID;
    float* H2  = H1 + (size_t)NROI * HID;
    float* BX2 = H2 + (size_t)NROI * HID;
    float* NB2 = BX2 + (size_t)NIMG * MCAND * 4;
    float* LV2 = NB2 + (size_t)NIMG * MCAND * 4;
    float* ksg = LV2 + (size_t)NIMG * MCAND;
    int*   kig = (int*)(ksg + (size_t)NIMG * 20 * NDET);
    int*   cntg = kig + (size_t)NIMG * 20 * NDET;

    roi_kernel<false><<<NROI, 256, 0, stream>>>(features, proposals, X, nullptr, nullptr);
    gemm1_kernel<<<dim3(16, 16, ZSPLIT), 256, 0, stream>>>(X, w1, CP);
    bias_relu_f32_kernel<<<(NROI * HID) / 256, 256, 0, stream>>>(CP, b1, H1);
    gemm2_kernel<<<dim3(16, 16), 256, 0, stream>>>(H1, w2, b2, H2);
    heads_kernel<<<NROI, 128, 0, stream>>>(H2, wc, bc, wb, bb, proposals,
                                           BX2, NB2, LV2);
    nms_class_kernel<<<NIMG * 20, 64, 0, stream>>>(NB2, LV2, ksg, kig, cntg);
    nms_merge_kernel<<<NIMG, 1024, 0, stream>>>(ksg, kig, cntg, BX2,
                                                (float*)d_out);
  }
}

// Round 8
// 788.868 us; speedup vs baseline: 1.0482x; 1.0482x over previous
//
#include <hip/hip_runtime.h>
#include <cmath>

// Problem constants (N=2, S=512, C=512, H=W=50, OUT=7, RATIO=2)
#define NIMG 2
#define SPROP 512
#define NROI 1024          // NIMG*SPROP
#define CCH 512
#define FH 50
#define FW 50
#define K1 25088           // CCH*7*7
#define HID 1024
#define NCLS 21
#define NDET 100
#define IMGSZ 800.0f
#define LOGMAX 4.135166556742356f   // log(1000/16)
#define MCAND 10240        // SPROP*(NCLS-1)
#define ZSPLIT 8
#define KCHUNK 3136        // K1/ZSPLIT
#define ZSPLIT2 8
#define KCHUNK2 128        // HID/ZSPLIT2

typedef unsigned short u16;
typedef __attribute__((ext_vector_type(8))) short short8;
typedef __attribute__((ext_vector_type(4))) float f32x4;
typedef __attribute__((ext_vector_type(16))) float f32x16;

__device__ __forceinline__ u16 f2bf(float x) {        // RTNE fp32 -> bf16
  unsigned int u = __float_as_uint(x);
  u += 0x7fffu + ((u >> 16) & 1u);
  return (u16)(u >> 16);
}
__device__ __forceinline__ float bf2f(u16 h) {
  return __uint_as_float(((unsigned int)h) << 16);
}

// async global->LDS, 16B per lane; LDS dest = wave-uniform base + lane*16.
__device__ __forceinline__ void gld16(const u16* g, u16* l) {
  __builtin_amdgcn_global_load_lds(
      (const __attribute__((address_space(1))) void*)g,
      (__attribute__((address_space(3))) void*)l, 16, 0, 0);
}

// ------------------------------------------------------------ ROI align
// r4 structure (worked: roi fell out of top-5). Per-axis factorized meta in
// float4, pair-reads, conflict-free strides (273/17), reg prefetch of next
// 32-ch slab.
template <bool BF16OUT>
__global__ __launch_bounds__(256) void roi_kernel(
    const float* __restrict__ feat, const float* __restrict__ props,
    float* __restrict__ X, u16* __restrict__ Xhi, u16* __restrict__ Xlo) {
  const int r = blockIdx.x;
  const int n = r >> 9;
  const int tid = threadIdx.x;
  __shared__ float tile[32 * 273 + 16];   // 32 ch x (16x17 px) +pad, ~35 KB
  __shared__ float4 ymeta[14];  // {asf(rowoff0), asf(rowoff1), wy0, wy1}
  __shared__ float4 xmeta[14];  // {asf(px0), wxa, wxb, 0}
  __shared__ int smin[2];       // ymin, xmin

  const float p0 = props[r * 4 + 0] * 0.0625f;
  const float p1 = props[r * 4 + 1] * 0.0625f;
  const float p2 = props[r * 4 + 2] * 0.0625f;
  const float p3 = props[r * 4 + 3] * 0.0625f;
  const float bw = fmaxf(p2 - p0, 1.0f) / 7.0f;
  const float bh = fmaxf(p3 - p1, 1.0f) / 7.0f;

  if (tid < 14) {               // y-axis metadata
    const int j = tid;
    const float g = (float)(j >> 1) + ((float)(j & 1) + 0.5f) * 0.5f;
    const float y = p1 + g * bh;
    const float vy = (y > -1.0f && y < (float)FH) ? 0.5f : 0.0f;  // fold 0.5
    const float yc = fminf(fmaxf(y, 0.0f), (float)(FH - 1));
    const int y0 = (int)floorf(yc);
    const int y1 = min(y0 + 1, FH - 1);
    const float ly = yc - (float)y0;
    const float yc0 = fminf(fmaxf(p1 + 0.25f * bh, 0.0f), (float)(FH - 1));
    const int ymin = (int)floorf(yc0);
    float4 m;
    m.x = __int_as_float((y0 - ymin) * 17);
    m.y = __int_as_float((y1 - ymin) * 17);
    m.z = (1.0f - ly) * vy;
    m.w = ly * vy;
    ymeta[j] = m;
    if (j == 0) smin[0] = ymin;
  } else if (tid >= 16 && tid < 30) {   // x-axis metadata
    const int j = tid - 16;
    const float g = (float)(j >> 1) + ((float)(j & 1) + 0.5f) * 0.5f;
    const float x = p0 + g * bw;
    const float vx = (x > -1.0f && x < (float)FW) ? 0.5f : 0.0f;
    const float xc = fminf(fmaxf(x, 0.0f), (float)(FW - 1));
    const int x0 = (int)floorf(xc);
    const int x1 = min(x0 + 1, FW - 1);
    const float lx = xc - (float)x0;
    const float xc0 = fminf(fmaxf(p0 + 0.25f * bw, 0.0f), (float)(FW - 1));
    const int xmin = (int)floorf(xc0);
    const float wx0 = (1.0f - lx) * vx;
    const float wx1 = lx * vx;
    const int d = x1 - x0;      // 0 or 1
    float4 m;
    m.x = __int_as_float(x0 - xmin);
    m.y = wx0 + (d ? 0.0f : wx1);   // wxa
    m.z = d ? wx1 : 0.0f;           // wxb
    m.w = 0.0f;
    xmeta[j] = m;
    if (j == 0) smin[1] = xmin;
  }
  __syncthreads();

  const int ymin = smin[0], xmin = smin[1];
  const float* fb = feat + (size_t)n * CCH * (FH * FW);
  const int gy = min(ymin + (tid >> 4), FH - 1);
  const int gx = min(xmin + (tid & 15), FW - 1);
  const int offp = gy * FW + gx;
  const int wslot = (tid >> 4) * 17 + (tid & 15);
  const int q = tid & 7;        // output-slot group
  const int c = tid >> 3;       // channel within slab (0..31)
  const int cb = c * 273;

  float pf[32];
#pragma unroll
  for (int e = 0; e < 32; ++e) pf[e] = fb[(size_t)e * (FH * FW) + offp];

  for (int cc = 0; cc < 16; ++cc) {
#pragma unroll
    for (int e = 0; e < 32; ++e) tile[e * 273 + wslot] = pf[e];
    __syncthreads();
    if (cc < 15) {
      const float* fb2 = fb + (size_t)(cc + 1) * 32 * (FH * FW);
#pragma unroll
      for (int e = 0; e < 32; ++e) pf[e] = fb2[(size_t)e * (FH * FW) + offp];
    }
#pragma unroll
    for (int jj = 0; jj < 7; ++jj) {
      const int s = q + (jj << 3);
      if (s < 49) {
        const int oy = s / 7;
        const int ox = s - oy * 7;
        const float4 ym0 = ymeta[2 * oy];
        const float4 ym1 = ymeta[2 * oy + 1];
        const float4 xm0 = xmeta[2 * ox];
        const float4 xm1 = xmeta[2 * ox + 1];
        float acc = 0.0f;
#pragma unroll
        for (int sy = 0; sy < 2; ++sy) {
          const float4 ym = sy ? ym1 : ym0;
          const int ro0 = cb + __float_as_int(ym.x);
          const int ro1 = cb + __float_as_int(ym.y);
#pragma unroll
          for (int sx = 0; sx < 2; ++sx) {
            const float4 xm = sx ? xm1 : xm0;
            const int px = __float_as_int(xm.x);
            const float a0 = tile[ro0 + px];
            const float a1 = tile[ro0 + px + 1];
            const float b0 = tile[ro1 + px];
            const float b1 = tile[ro1 + px + 1];
            acc += ym.z * (xm.y * a0 + xm.z * a1) +
                   ym.w * (xm.y * b0 + xm.z * b1);
          }
        }
        const size_t k = (size_t)r * K1 + (size_t)(cc * 32 + c) * 49 + s;
        if (BF16OUT) {
          const u16 h = f2bf(acc);
          Xhi[k] = h;
          Xlo[k] = f2bf(acc - bf2f(h));
        } else {
          X[k] = acc;
        }
      }
    }
    __syncthreads();
  }
}

// ------------------------- w -> hi/lo bf16, transposed to [n][k]
template <int KDIM>
__global__ __launch_bounds__(256) void convw_kernel(
    const float* __restrict__ w, u16* __restrict__ Wh, u16* __restrict__ Wl) {
  __shared__ u16 sh[64][65], sl[64][65];
  const int k0 = blockIdx.x * 64;
  const int n0 = blockIdx.y * 64;
  const int t = threadIdx.x;
#pragma unroll
  for (int e = 0; e < 16; ++e) {
    const int idx = t + e * 256;
    const int kl = idx >> 6, nl = idx & 63;
    const float v = w[(size_t)(k0 + kl) * HID + n0 + nl];
    const u16 h = f2bf(v);
    sh[kl][nl] = h;
    sl[kl][nl] = f2bf(v - bf2f(h));
  }
  __syncthreads();
#pragma unroll
  for (int e = 0; e < 16; ++e) {
    const int idx = t + e * 256;
    const int nl = idx >> 6, kl = idx & 63;
    Wh[(size_t)(n0 + nl) * KDIM + k0 + kl] = sh[kl][nl];
    Wl[(size_t)(n0 + nl) * KDIM + k0 + kl] = sl[kl][nl];
  }
}

// --------------- split-bf16 MFMA GEMM (32x32x16), generic K-stride / K-chunk
// Round-15: faithful m201 8-phase-class schedule. History: every 2-barrier
// variant hit the documented m97 ceiling (r1 853 / r2 883 / r4 882 TF of
// MFMA-pipe work); r5/r7's COARSE phase-split regressed exactly as m196
// predicts (-7..27%). This round ports the fine interleave:
//  * per K=32 step -> 2 phases (kh=0/1), each the m201 template shape:
//    {8 ds_read_b128 frags | 3 gld16 prefetch} -> s_barrier -> lgkmcnt(0)
//    -> sched_barrier -> setprio(1) 12 MFMA setprio(0) -> s_barrier.
//    (m201's per-phase mix: 4-8 reads, ~2 stages, 12-16 MFMAs.)
//  * TRIPLE-buffered LDS (3 x 48KB = 144KB), prefetch depth 2: steady state
//    keeps 12 DMAs in flight; vmcnt(6) ONCE per K-step at phase-1 end (its
//    trailing barrier doubles as the staging-confirm barrier). Never drains
//    to 0 mid-loop; retired buffer's loads were issued a full K-step earlier.
//  * Hazards: overwritten buffer (rotation) was fully read one step earlier
//    (lgkmcnt(0) precedes its MFMAs, trailing barrier follows); per-wave
//    vmcnt + s_barrier gives cross-wave DMA visibility; tail peels to
//    vmcnt(0) when prefetch stops.
// Data layout identical to r7 (verified passing): linear LDS dest (DMA),
// global source col pre-swizzled (chunk ^ ((row>>1)&3)), read-side vswz.
// A/B frag: [row = lane&31][k = (lane>>5)*8 + j].
// C/D: col = lane&31, row = (reg&3) + 8*(reg>>2) + 4*(lane>>5)  [m74/m101].
template <int KS, int KCH, bool SWZ>
__global__ __launch_bounds__(512, 2) void gemm_mfma_split(
    const u16* __restrict__ Ahg, const u16* __restrict__ Alg,
    const u16* __restrict__ Bhg, const u16* __restrict__ Blg,
    float* __restrict__ CP) {
  __shared__ u16 Ah[3][128][32], Al[3][128][32];
  __shared__ u16 Bh[3][256][32], Bl[3][256][32];
  const int tid = threadIdx.x;
  const int lane = tid & 63;
  const int wv = tid >> 6;           // 0..7
  const int wm = (wv >> 2) << 6;     // A row band {0,64}
  const int wn = (wv & 3) << 6;      // B col band {0,64,128,192}

  int bx = blockIdx.x, by = blockIdx.y, bz = blockIdx.z;
  if (SWZ) {
    // grid must be (4,8,8): XCD (= flat%8 under round-robin dispatch) <-> z.
    const int f = blockIdx.x + ((blockIdx.y + (blockIdx.z << 3)) << 2);
    bz = f & 7;
    const int u = f >> 3;            // 0..31
    bx = u & 3;
    by = u >> 2;
  }
  const int mT = by << 7;            // 128-row tiles
  const int nT = bx << 8;            // 256-col tiles
  const int kz = bz * KCH;
  constexpr int NSTEP = KCH / 32;    // >= 2 for both instantiations

  // staging thread map: row sr = tid>>2, 16B chunk tid&3; LDS dest linear
  // (base + tid*16B), global col pre-swizzled (both-sides involution).
  const int sr = tid >> 2;                                  // 0..127
  const int sqw = (((tid & 3) ^ ((tid >> 3) & 3)) << 3);    // swizzled src col
  const size_t aoff  = (size_t)(mT + sr) * KS + sqw;
  const size_t b0off = (size_t)(nT + sr) * KS + sqw;
  const size_t b1off = (size_t)(nT + sr + 128) * KS + sqw;
  const int lofs = tid * 8;          // u16 units = tid*16 bytes

  f32x16 acc[2][2];
#pragma unroll
  for (int i = 0; i < 2; ++i)
#pragma unroll
    for (int j = 0; j < 2; ++j)
#pragma unroll
      for (int e = 0; e < 16; ++e) acc[i][j][e] = 0.0f;

  const int fm = lane & 31;          // row within 32-tile
  const int fh = lane >> 5;          // k-subgroup (0/1)
  const int vswz = (fm >> 1) & 3;    // read-side swizzle (row-derived)

  auto stage3a = [&](int buf, int kb) {   // phase-0 half
    gld16(Ahg + aoff + kb, &Ah[buf][0][0] + lofs);
    gld16(Alg + aoff + kb, &Al[buf][0][0] + lofs);
    gld16(Bhg + b0off + kb, &Bh[buf][0][0] + lofs);
  };
  auto stage3b = [&](int buf, int kb) {   // phase-1 half
    gld16(Bhg + b1off + kb, &Bh[buf][128][0] + lofs);
    gld16(Blg + b0off + kb, &Bl[buf][0][0] + lofs);
    gld16(Blg + b1off + kb, &Bl[buf][128][0] + lofs);
  };

  // one phase: read 8 frags (kh fixed) | stage 3 | bar | lgkm0 | 12 MFMA | bar
  auto phase = [&](int buf, int kh, bool st, int stbuf, int stkb, bool half_a) {
    const int cA = ((((kh << 1) | fh) ^ vswz) << 3);
    short8 fa_h[2], fa_l[2], fb_h[2], fb_l[2];
#pragma unroll
    for (int t = 0; t < 2; ++t) {
      fa_h[t] = *(const short8*)(&Ah[buf][wm + t * 32 + fm][cA]);
      fa_l[t] = *(const short8*)(&Al[buf][wm + t * 32 + fm][cA]);
      fb_h[t] = *(const short8*)(&Bh[buf][wn + t * 32 + fm][cA]);
      fb_l[t] = *(const short8*)(&Bl[buf][wn + t * 32 + fm][cA]);
    }
    if (st) {
      if (half_a) stage3a(stbuf, stkb);
      else        stage3b(stbuf, stkb);
    }
    __builtin_amdgcn_s_barrier();
    asm volatile("s_waitcnt lgkmcnt(0)" ::: "memory");
    __builtin_amdgcn_sched_barrier(0);
    __builtin_amdgcn_s_setprio(1);
#pragma unroll
    for (int ti = 0; ti < 2; ++ti)
#pragma unroll
      for (int tj = 0; tj < 2; ++tj) {
        acc[ti][tj] = __builtin_amdgcn_mfma_f32_32x32x16_bf16(
            fa_h[ti], fb_h[tj], acc[ti][tj], 0, 0, 0);
        acc[ti][tj] = __builtin_amdgcn_mfma_f32_32x32x16_bf16(
            fa_h[ti], fb_l[tj], acc[ti][tj], 0, 0, 0);
        acc[ti][tj] = __builtin_amdgcn_mfma_f32_32x32x16_bf16(
            fa_l[ti], fb_h[tj], acc[ti][tj], 0, 0, 0);
      }
    __builtin_amdgcn_s_setprio(0);
    __builtin_amdgcn_sched_barrier(0);
  };

  // prologue: stage buffers 0 (k0) and 1 (k1); confirm buffer 0 only.
  stage3a(0, kz);
  stage3b(0, kz);
  stage3a(1, kz + 32);
  stage3b(1, kz + 32);
  asm volatile("s_waitcnt vmcnt(6)" ::: "memory");   // retire buf0's 6
  __builtin_amdgcn_s_barrier();

  int c0 = 0, c1 = 1, c2 = 2;
  for (int s = 0; s < NSTEP; ++s) {
    const int kb2 = kz + (s + 2) * 32;
    const bool st = (s + 2 < NSTEP);
    // ---- phase 0 (kh = 0): frags from c0, stage first half into c2
    phase(c0, 0, st, c2, kb2, true);
    __builtin_amdgcn_s_barrier();
    // ---- phase 1 (kh = 1): frags from c0, stage second half into c2
    phase(c0, 1, st, c2, kb2, false);
    // confirm NEXT step's buffer (c1) before its phase-0 reads:
    // steady: outstanding = {c1:6, c2:6} -> vmcnt(6) retires c1's.
    // tail (no c2 staged): outstanding = {c1:6} -> vmcnt(0).
    if (st) {
      asm volatile("s_waitcnt vmcnt(6)" ::: "memory");
    } else if (s + 1 < NSTEP) {
      asm volatile("s_waitcnt vmcnt(0)" ::: "memory");
    }
    __builtin_amdgcn_s_barrier();
    const int t = c0; c0 = c1; c1 = c2; c2 = t;      // rotate buffers
  }

  float* Cp = CP + (size_t)bz * ((size_t)NROI * HID);   // bz: swizzled!
  const int ccol = nT + wn + fm;
  const int rbase = mT + wm + (fh << 2);
#pragma unroll
  for (int ti = 0; ti < 2; ++ti)
#pragma unroll
    for (int tj = 0; tj < 2; ++tj)
#pragma unroll
      for (int rg = 0; rg < 16; ++rg) {
        const int row = rbase + ti * 32 + (rg & 3) + 8 * (rg >> 2);
        Cp[(size_t)row * HID + ccol + tj * 32] = acc[ti][tj][rg];
      }
}

// ------------------------------------------------------- FC1 fallback (fp32)
__global__ __launch_bounds__(256) void gemm1_kernel(
    const float* __restrict__ A, const float* __restrict__ B,
    float* __restrict__ CP) {
  __shared__ float As[16][68];
  __shared__ float Bs[16][68];
  const int tid = threadIdx.x;
  const int mTile = blockIdx.y << 6;
  const int nTile = blockIdx.x << 6;
  const int k0 = blockIdx.z * KCHUNK;
  const int ty = tid >> 4, tx = tid & 15;
  const int ar = tid >> 2, ac = (tid & 3) << 2;
  const int br = tid >> 4, bcl = (tid & 15) << 2;
  float acc[4][4] = {};

  for (int kb = k0; kb < k0 + KCHUNK; kb += 16) {
    const float4 av = *(const float4*)(A + (size_t)(mTile + ar) * K1 + kb + ac);
    const float4 bv = *(const float4*)(B + (size_t)(kb + br) * HID + nTile + bcl);
    As[ac + 0][ar] = av.x; As[ac + 1][ar] = av.y;
    As[ac + 2][ar] = av.z; As[ac + 3][ar] = av.w;
    *(float4*)(&Bs[br][bcl]) = bv;
    __syncthreads();
#pragma unroll
    for (int kk = 0; kk < 16; ++kk) {
      const float4 a4 = *(const float4*)(&As[kk][ty << 2]);
      const float4 b4 = *(const float4*)(&Bs[kk][tx << 2]);
      const float aa[4] = {a4.x, a4.y, a4.z, a4.w};
      const float bb4[4] = {b4.x, b4.y, b4.z, b4.w};
#pragma unroll
      for (int i = 0; i < 4; ++i)
#pragma unroll
        for (int j = 0; j < 4; ++j)
          acc[i][j] = fmaf(aa[i], bb4[j], acc[i][j]);
    }
    __syncthreads();
  }
  float* Cp = CP + (size_t)blockIdx.z * (HID * NROI);
#pragma unroll
  for (int i = 0; i < 4; ++i) {
    *(float4*)(Cp + (size_t)(mTile + (ty << 2) + i) * HID + nTile + (tx << 2)) =
        make_float4(acc[i][0], acc[i][1], acc[i][2], acc[i][3]);
  }
}

// reduce 8 K-partials + bias + relu -> H1 as split-bf16 (feeds FC2 MFMA)
__global__ __launch_bounds__(256) void bias_relu_bf16_kernel(
    const float* __restrict__ CP, const float* __restrict__ b1,
    u16* __restrict__ H1h, u16* __restrict__ H1l) {
  const int idx = blockIdx.x * 256 + threadIdx.x;
  float v = b1[idx & (HID - 1)];
#pragma unroll
  for (int z = 0; z < ZSPLIT; ++z) v += CP[(size_t)z * (HID * NROI) + idx];
  v = fmaxf(v, 0.0f);
  const u16 h = f2bf(v);
  H1h[idx] = h;
  H1l[idx] = f2bf(v - bf2f(h));
}

// fp32 variant for the fallback path
__global__ __launch_bounds__(256) void bias_relu_f32_kernel(
    const float* __restrict__ CP, const float* __restrict__ b1,
    float* __restrict__ H1) {
  const int idx = blockIdx.x * 256 + threadIdx.x;
  float v = b1[idx & (HID - 1)];
#pragma unroll
  for (int z = 0; z < ZSPLIT; ++z) v += CP[(size_t)z * (HID * NROI) + idx];
  H1[idx] = fmaxf(v, 0.0f);
}

// reduce 8 K-partials of FC2 + bias + relu -> H2 fp32
__global__ __launch_bounds__(256) void bias_relu2_kernel(
    const float* __restrict__ CP2, const float* __restrict__ b2,
    float* __restrict__ H2) {
  const int idx = blockIdx.x * 256 + threadIdx.x;
  float v = b2[idx & (HID - 1)];
#pragma unroll
  for (int z = 0; z < ZSPLIT2; ++z) v += CP2[(size_t)z * (HID * NROI) + idx];
  H2[idx] = fmaxf(v, 0.0f);
}

// ------------------------------------------------------------- FC2 (K=1024)
// fp32 fallback only (bf16 path uses gemm_mfma_split<HID, KCHUNK2, true>)
__global__ __launch_bounds__(256) void gemm2_kernel(
    const float* __restrict__ A, const float* __restrict__ B,
    const float* __restrict__ bias, float* __restrict__ C) {
  __shared__ float As[16][68];
  __shared__ float Bs[16][68];
  const int tid = threadIdx.x;
  const int mTile = blockIdx.y << 6;
  const int nTile = blockIdx.x << 6;
  const int ty = tid >> 4, tx = tid & 15;
  const int ar = tid >> 2, ac = (tid & 3) << 2;
  const int br = tid >> 4, bcl = (tid & 15) << 2;
  float acc[4][4] = {};

  for (int kb = 0; kb < HID; kb += 16) {
    const float4 av = *(const float4*)(A + (size_t)(mTile + ar) * HID + kb + ac);
    const float4 bv = *(const float4*)(B + (size_t)(kb + br) * HID + nTile + bcl);
    As[ac + 0][ar] = av.x; As[ac + 1][ar] = av.y;
    As[ac + 2][ar] = av.z; As[ac + 3][ar] = av.w;
    *(float4*)(&Bs[br][bcl]) = bv;
    __syncthreads();
#pragma unroll
    for (int kk = 0; kk < 16; ++kk) {
      const float4 a4 = *(const float4*)(&As[kk][ty << 2]);
      const float4 b4 = *(const float4*)(&Bs[kk][tx << 2]);
      const float aa[4] = {a4.x, a4.y, a4.z, a4.w};
      const float bb4[4] = {b4.x, b4.y, b4.z, b4.w};
#pragma unroll
      for (int i = 0; i < 4; ++i)
#pragma unroll
        for (int j = 0; j < 4; ++j)
          acc[i][j] = fmaf(aa[i], bb4[j], acc[i][j]);
    }
    __syncthreads();
  }
#pragma unroll
  for (int i = 0; i < 4; ++i) {
#pragma unroll
    for (int j = 0; j < 4; ++j) {
      float v = acc[i][j] + bias[nTile + (tx << 2) + j];
      acc[i][j] = fmaxf(v, 0.0f);
    }
    *(float4*)(C + (size_t)(mTile + (ty << 2) + i) * HID + nTile + (tx << 2)) =
        make_float4(acc[i][0], acc[i][1], acc[i][2], acc[i][3]);
  }
}

// ------------------- heads: cls+box dots, softmax, decode, candidate arrays
// Candidate layout is CLASS-MAJOR: index = n*MCAND + (k-1)*SPROP + s
__global__ __launch_bounds__(128) void heads_kernel(
    const float* __restrict__ H2m, const float* __restrict__ wc,
    const float* __restrict__ bc, const float* __restrict__ wb,
    const float* __restrict__ bb, const float* __restrict__ props,
    float* __restrict__ BX2, float* __restrict__ NB2,
    float* __restrict__ LV2) {
  const int r = blockIdx.x;
  const int tid = threadIdx.x;
  __shared__ float hrow[HID];
  __shared__ float vals[112];
  __shared__ float red[2];

  for (int i = tid; i < HID; i += 128) hrow[i] = H2m[(size_t)r * HID + i];
  __syncthreads();

  if (tid < 105) {
    float acc;
    if (tid < NCLS) {
      acc = bc[tid];
      for (int kk = 0; kk < HID; ++kk) acc = fmaf(hrow[kk], wc[kk * NCLS + tid], acc);
    } else {
      const int j = tid - NCLS;
      acc = bb[j];
      for (int kk = 0; kk < HID; ++kk) acc = fmaf(hrow[kk], wb[kk * (NCLS * 4) + j], acc);
    }
    vals[tid] = acc;
  }
  __syncthreads();

  if (tid == 0) {
    float m = vals[0];
    for (int k = 1; k < NCLS; ++k) m = fmaxf(m, vals[k]);
    float s = 0.0f;
    for (int k = 0; k < NCLS; ++k) s += expf(vals[k] - m);
    red[0] = m;
    red[1] = 1.0f / s;
  }
  __syncthreads();

  if (tid >= 1 && tid <= 20) {
    const int k = tid;
    const float prob = expf(vals[k] - red[0]) * red[1];

    const float px1 = props[r * 4 + 0], py1 = props[r * 4 + 1];
    const float px2 = props[r * 4 + 2], py2 = props[r * 4 + 3];
    const float pw = px2 - px1, ph = py2 - py1;
    const float pcx = px1 + 0.5f * pw, pcy = py1 + 0.5f * ph;

    const float dx = vals[NCLS + k * 4 + 0] / 10.0f;
    const float dy = vals[NCLS + k * 4 + 1] / 10.0f;
    const float dw = fminf(vals[NCLS + k * 4 + 2] / 5.0f, LOGMAX);
    const float dh = fminf(vals[NCLS + k * 4 + 3] / 5.0f, LOGMAX);

    const float cx = dx * pw + pcx, cy = dy * ph + pcy;
    const float w = expf(dw) * pw, h = expf(dh) * ph;
    float b0 = cx - 0.5f * w, b1c = cy - 0.5f * h;
    float b2 = cx + 0.5f * w, b3 = cy + 0.5f * h;
    b0 = fminf(fmaxf(b0, 0.0f), IMGSZ);
    b1c = fminf(fmaxf(b1c, 0.0f), IMGSZ);
    b2 = fminf(fmaxf(b2, 0.0f), IMGSZ);
    b3 = fminf(fmaxf(b3, 0.0f), IMGSZ);

    const float wv = b2 - b0, hv = b3 - b1c;
    const bool valid = (prob > 0.05f) && (wv >= 0.01f) && (hv >= 0.01f);

    const int n = r >> 9, s = r & 511;
    const int cand = (k - 1) * SPROP + s;     // class-major
    const size_t bi = (size_t)n * MCAND + cand;
    const float off = (float)k * (IMGSZ + 1.0f);

    BX2[bi * 4 + 0] = b0; BX2[bi * 4 + 1] = b1c;
    BX2[bi * 4 + 2] = b2; BX2[bi * 4 + 3] = b3;
    NB2[bi * 4 + 0] = b0 + off; NB2[bi * 4 + 1] = b1c + off;
    NB2[bi * 4 + 2] = b2 + off; NB2[bi * 4 + 3] = b3 + off;
    LV2[bi] = valid ? prob : -1.0f;
  }
}

// ---------------------------------------------- per-(image,class) greedy NMS
// Cross-class IoU == 0 (801*k offsets), so the global greedy restricted to a
// class equals the standalone per-class greedy (proved by induction on picks).
// One wave per (n,c): 512 slots in registers, barrier-free serial loop.
template <int CTRL>
__device__ __forceinline__ void red2(float& v, int& ix) {
  const float tv = __int_as_float(__builtin_amdgcn_update_dpp(
      (int)0xC0000000, __float_as_int(v), CTRL, 0xf, 0xf, false));
  const int ti = __builtin_amdgcn_update_dpp(0x7fffffff, ix, CTRL, 0xf, 0xf, false);
  if (tv > v || (tv == v && ti < ix)) { v = tv; ix = ti; }
}
__device__ __forceinline__ void wave_red2(float& v, int& ix) {
  red2<0x111>(v, ix);  // row_shr:1
  red2<0x112>(v, ix);  // row_shr:2
  red2<0x114>(v, ix);  // row_shr:4
  red2<0x118>(v, ix);  // row_shr:8
  red2<0x142>(v, ix);  // row_bcast:15
  red2<0x143>(v, ix);  // row_bcast:31 -> lane 63 holds winner
}

__global__ __launch_bounds__(64) void nms_class_kernel(
    const float* __restrict__ NB2, const float* __restrict__ LV2,
    float* __restrict__ ksg, int* __restrict__ kig, int* __restrict__ cntg) {
  const int bid = blockIdx.x;           // n*20 + c
  const int lane = threadIdx.x;         // 0..63
  __shared__ float4 lbox[SPROP];        // winner-broadcast copy
  const size_t cb = (size_t)bid * SPROP;

  float lv[8], b0[8], b1[8], b2[8], b3[8], ar[8];
#pragma unroll
  for (int j = 0; j < 8; ++j) {
    const int s = lane + j * 64;
    lv[j] = LV2[cb + s];
    const float4 b = *(const float4*)(NB2 + (cb + s) * 4);
    b0[j] = b.x; b1[j] = b.y; b2[j] = b.z; b3[j] = b.w;
    ar[j] = (b.z - b.x) * (b.w - b.y);
    lbox[s] = b;
  }

  int cnt = 0;
  for (int d = 0; d < NDET; ++d) {
    float bv = -2.0f;
    int bix = 0x7fffffff;
#pragma unroll
    for (int j = 0; j < 8; ++j) {     // j asc => slot asc; strict > keeps lowest
      if (lv[j] > bv) { bv = lv[j]; bix = lane + j * 64; }
    }
    wave_red2(bv, bix);
    const float bv2 = __shfl(bv, 63);
    const int bix2 = __shfl(bix, 63);
    if (bv2 <= 0.05f) break;          // all remaining dead; wave-uniform

    if (lane == 0) {
      ksg[bid * NDET + cnt] = bv2;
      kig[bid * NDET + cnt] = bix2;   // slot within class (0..511)
    }
    ++cnt;

    const float4 wb = lbox[bix2];     // same-wave LDS write->read, waitcnt ok
    const float wa = (wb.z - wb.x) * (wb.w - wb.y);
#pragma unroll
    for (int j = 0; j < 8; ++j) {
      const float xx1 = fmaxf(wb.x, b0[j]);
      const float yy1 = fmaxf(wb.y, b1[j]);
      const float xx2 = fminf(wb.z, b2[j]);
      const float yy2 = fminf(wb.w, b3[j]);
      const float inter = fmaxf(xx2 - xx1, 0.0f) * fmaxf(yy2 - yy1, 0.0f);
      const float iou = inter / (wa + ar[j] - inter + 1e-9f);
      if (iou > 0.5f) lv[j] = -1.0f;
    }
  }
  if (lane == 0) cntg[bid] = cnt;
}

// ------------------------------- merge: top-100 by (score desc, flat-idx asc)
// Global greedy order == keeps sorted by packed priority (scores non-increasing
// along greedy; tied keeps are simultaneously live so argmax first-index rule
// = lowest flat idx). Rank-based selection: zero barriers in the hot loop.
__global__ __launch_bounds__(1024) void nms_merge_kernel(
    const float* __restrict__ ksg, const int* __restrict__ kig,
    const int* __restrict__ cntg, const float* __restrict__ BX2,
    float* __restrict__ out) {
  const int n = blockIdx.x;
  const int tid = threadIdx.x;
  __shared__ int cbase[21];
  __shared__ unsigned long long keys[2000];
  __shared__ float ssc[2000];
  __shared__ int sfl[2000];
  __shared__ float svals[NDET];
  __shared__ int sflat[NDET];

  if (tid == 0) {
    int acc = 0;
    for (int c = 0; c < 20; ++c) { cbase[c] = acc; acc += cntg[n * 20 + c]; }
    cbase[20] = acc;
  }
  __syncthreads();
  const int T = cbase[20];     // <= 2000

  for (int idx = tid; idx < 20 * NDET; idx += 1024) {
    const int c = idx / NDET, e = idx - (idx / NDET) * NDET;
    if (e < cntg[n * 20 + c]) {
      const int pos = cbase[c] + e;
      const float s = ksg[(n * 20 + c) * NDET + e];
      const int slot = kig[(n * 20 + c) * NDET + e];
      const int flat = slot * 20 + c;            // original flat candidate idx
      ssc[pos] = s;
      sfl[pos] = flat;
      keys[pos] = ((unsigned long long)__float_as_uint(s) << 32) |
                  (unsigned long long)(0xFFFFFFFFu - (unsigned)flat);
    }
  }
  __syncthreads();

  float msc[2]; int mfl[2]; unsigned long long mk[2]; int rank[2] = {0, 0};
  bool own[2];
#pragma unroll
  for (int e = 0; e < 2; ++e) {
    const int i = tid + e * 1024;
    own[e] = (i < T);
    if (own[e]) { mk[e] = keys[i]; msc[e] = ssc[i]; mfl[e] = sfl[i]; }
  }
  for (int i = 0; i < T; ++i) {        // LDS broadcast read per iteration
    const unsigned long long k = keys[i];
    if (own[0] && k > mk[0]) ++rank[0];
    if (own[1] && k > mk[1]) ++rank[1];
  }
#pragma unroll
  for (int e = 0; e < 2; ++e)
    if (own[e] && rank[e] < NDET) { svals[rank[e]] = msc[e]; sflat[rank[e]] = mfl[e]; }
  __syncthreads();

  if (tid < NDET) {
    const int m = (T < NDET) ? T : NDET;
    const bool keep = tid < m;
    float sv = 0.0f;
    float4 bx4 = make_float4(0.0f, 0.0f, 0.0f, 0.0f);
    float label = 0.0f;
    if (keep) {
      sv = svals[tid];
      const int flat = sflat[tid];
      const int c = flat % 20, s = flat / 20;
      bx4 = *(const float4*)(BX2 + ((size_t)(n * 20 + c) * SPROP + s) * 4);
      label = (float)(c + 1);
    }
    out[(n * NDET + tid) * 4 + 0] = bx4.x;
    out[(n * NDET + tid) * 4 + 1] = bx4.y;
    out[(n * NDET + tid) * 4 + 2] = bx4.z;
    out[(n * NDET + tid) * 4 + 3] = bx4.w;
    out[NIMG * NDET * 4 + n * NDET + tid] = sv;
    out[NIMG * NDET * 4 + NIMG * NDET + n * NDET + tid] = label;
  }
}

// ---------------------------------------------------------------- launcher
extern "C" void kernel_launch(void* const* d_in, const int* in_sizes, int n_in,
                              void* d_out, int out_size, void* d_ws, size_t ws_size,
                              hipStream_t stream) {
  const float* features  = (const float*)d_in[0];
  const float* proposals = (const float*)d_in[1];
  const float* w1 = (const float*)d_in[2];
  const float* b1 = (const float*)d_in[3];
  const float* w2 = (const float*)d_in[4];
  const float* b2 = (const float*)d_in[5];
  const float* wc = (const float*)d_in[6];
  const float* bc = (const float*)d_in[7];
  const float* wb = (const float*)d_in[8];
  const float* bb = (const float*)d_in[9];

  const size_t XE = (size_t)NROI * K1;
  const size_t WE = (size_t)K1 * HID;
  const size_t FLOATS_TAIL =
      (size_t)ZSPLIT * NROI * HID + 2 * (size_t)NROI * HID + (size_t)NIMG * MCAND * 10;
  const size_t NEED = (XE * 2 + WE * 2) * sizeof(u16) + FLOATS_TAIL * sizeof(float);

  if (ws_size >= NEED) {
    u16* Xhi = (u16*)d_ws;
    u16* Xlo = Xhi + XE;
    u16* Wh  = Xlo + XE;
    u16* Wl  = Wh + WE;
    float* CP  = (float*)(Wl + WE);
    // CP region: 8 partials (33.5 MB); FC2's 8 partials (CP2) alias it —
    // CP is dead after bias_relu_bf16, CP2 written only by the later FC2.
    float* CP2 = CP;
    float* H2  = CP + (size_t)ZSPLIT * NROI * HID;
    float* BX2 = H2 + (size_t)NROI * HID;
    float* NB2 = BX2 + (size_t)NIMG * MCAND * 4;
    float* LV2 = NB2 + (size_t)NIMG * MCAND * 4;
    float* ksg = LV2 + (size_t)NIMG * MCAND;
    int*   kig = (int*)(ksg + (size_t)NIMG * 20 * NDET);
    int*   cntg = kig + (size_t)NIMG * 20 * NDET;
    // H1 hi/lo alias the Xhi region (dead after FC1); W2t hi/lo alias Xlo.
    // Stream order guarantees safety: gemm1 reads X before these are written.
    u16* H1h = Xhi;
    u16* H1l = Xhi + (size_t)NROI * HID;
    u16* W2h = Xlo;
    u16* W2l = Xlo + (size_t)HID * HID;

    convw_kernel<K1><<<dim3(K1 / 64, HID / 64), 256, 0, stream>>>(w1, Wh, Wl);
    roi_kernel<true><<<NROI, 256, 0, stream>>>(features, proposals, nullptr, Xhi, Xlo);
    gemm_mfma_split<K1, KCHUNK, true><<<dim3(4, 8, ZSPLIT), 512, 0, stream>>>(
        Xhi, Xlo, Wh, Wl, CP);
    bias_relu_bf16_kernel<<<(NROI * HID) / 256, 256, 0, stream>>>(CP, b1, H1h, H1l);
    convw_kernel<HID><<<dim3(HID / 64, HID / 64), 256, 0, stream>>>(w2, W2h, W2l);
    gemm_mfma_split<HID, KCHUNK2, true><<<dim3(4, 8, ZSPLIT2), 512, 0, stream>>>(
        H1h, H1l, W2h, W2l, CP2);
    bias_relu2_kernel<<<(NROI * HID) / 256, 256, 0, stream>>>(CP2, b2, H2);
    heads_kernel<<<NROI, 128, 0, stream>>>(H2, wc, bc, wb, bb, proposals,
                                           BX2, NB2, LV2);
    nms_class_kernel<<<NIMG * 20, 64, 0, stream>>>(NB2, LV2, ksg, kig, cntg);
    nms_merge_kernel<<<NIMG, 1024, 0, stream>>>(ksg, kig, cntg, BX2,
                                                (float*)d_out);
  } else {
    float* ws = (float*)d_ws;
    float* X   = ws;
    float* CP  = X + XE;
    float* H1  = CP + (size_t)ZSPLIT * NROI * HID;
    float* H2  = H1 + (size_t)NROI * HID;
    float* BX2 = H2 + (size_t)NROI * HID;
    float* NB2 = BX2 + (size_t)NIMG * MCAND * 4;
    float* LV2 = NB2 + (size_t)NIMG * MCAND * 4;
    float* ksg = LV2 + (size_t)NIMG * MCAND;
    int*   kig = (int*)(ksg + (size_t)NIMG * 20 * NDET);
    int*   cntg = kig + (size_t)NIMG * 20 * NDET;

    roi_kernel<false><<<NROI, 256, 0, stream>>>(features, proposals, X, nullptr, nullptr);
    gemm1_kernel<<<dim3(16, 16, ZSPLIT), 256, 0, stream>>>(X, w1, CP);
    bias_relu_f32_kernel<<<(NROI * HID) / 256, 256, 0, stream>>>(CP, b1, H1);
    gemm2_kernel<<<dim3(16, 16), 256, 0, stream>>>(H1, w2, b2, H2);
    heads_kernel<<<NROI, 128, 0, stream>>>(H2, wc, bc, wb, bb, proposals,
                                           BX2, NB2, LV2);
    nms_class_kernel<<<NIMG * 20, 64, 0, stream>>>(NB2, LV2, ksg, kig, cntg);
    nms_merge_kernel<<<NIMG, 1024, 0, stream>>>(ksg, kig, cntg, BX2,
                                                (float*)d_out);
  }
}